// Round 1
// 787.412 us; speedup vs baseline: 1.0167x; 1.0167x over previous
//
#include <hip/hip_runtime.h>

typedef __bf16 bf16;
typedef __bf16 bf16x4 __attribute__((ext_vector_type(4)));
typedef __bf16 bf16x8 __attribute__((ext_vector_type(8)));
typedef float f32x4 __attribute__((ext_vector_type(4)));

#define HID 4096
#define QKV_N 6144
#define NTOK 4096   // b*s = 4*1024

// async global->LDS, 16B per lane. LDS side is wave-uniform base + lane*16.
__device__ __forceinline__ void gload_lds16(const bf16* g, bf16* l) {
  __builtin_amdgcn_global_load_lds(
      (__attribute__((address_space(1))) void*)(g),
      (__attribute__((address_space(3))) void*)(l), 16, 0, 0);
}

// ---------------- fp32 -> bf16 convert ----------------
__global__ void cvt_kernel(const float4* __restrict__ s, bf16x4* __restrict__ d) {
  int i = blockIdx.x * blockDim.x + threadIdx.x;
  float4 v = s[i];
  bf16x4 o;
  o[0] = (bf16)v.x; o[1] = (bf16)v.y; o[2] = (bf16)v.z; o[3] = (bf16)v.w;
  d[i] = o;
}

// ---------------- GEMM: C = A @ B^T, 256x256 tile, 8-phase counted-vmcnt ----------------
// 8 waves (2M x 4N), each owns a 128x64 output. BK=64, double-buffered LDS
// (128 KiB -> 1 block/CU). Octet-XOR swizzle (proven 0-conflict in prior rounds):
// source k-octet pre-XORed with row&7, LDS linear, read XORs back.
// Pipeline: per K-tile t (buf p=t&1), 4 phases {dsread | stage | bar | lgkm |
// setprio MFMA | bar}; stage slots: ph1 -> (t+1).A1 into p^1; ph3 -> (t+2).B0,B1
// into p (B region retired after ph2); ph4 -> (t+2).A0 into p (A retired after
// ph3). vmcnt(6) once per tile at ph4 => 3 half-tiles stay in flight across
// barriers; min issue->deadline distance = 3 phases.
template <typename OutT>
__global__ __launch_bounds__(512, 2) void gemm_bt256(
    const bf16* __restrict__ A, const bf16* __restrict__ Bm,
    OutT* __restrict__ C, int M, int N, int K)
{
  __shared__ __align__(16) bf16 As[2][256 * 64];
  __shared__ __align__(16) bf16 Bs[2][256 * 64];

  const int tid = threadIdx.x;
  const int w = tid >> 6, l = tid & 63;
  const int quad = l >> 4, lane16 = l & 15;
  const int sw = lane16 & 7;        // read-side swizzle key (row & 7)
  const int lrow = l >> 3;          // staging: row within 8-row chunk
  const int lk = (l & 7) ^ lrow;    // staging: pre-swizzled source k-octet

  // XCD-aware bijective swizzle (grid sizes here are multiples of 8)
  const int nwg = gridDim.x * gridDim.y;
  int bid = blockIdx.y * gridDim.x + blockIdx.x;
  bid = (bid & 7) * (nwg >> 3) + (bid >> 3);
  const int row0 = (bid / gridDim.x) * 256;
  const int col0 = (bid % gridDim.x) * 256;

  const int wm = (w >> 2) * 128;    // wave M offset (0 / 128)
  const int wn = (w & 3) * 64;      // wave N offset (0/64/128/192)

  f32x4 acc[2][2][4][2];            // [mq][nq][im][in_]
#pragma unroll
  for (int mq = 0; mq < 2; ++mq)
#pragma unroll
    for (int nq = 0; nq < 2; ++nq)
#pragma unroll
      for (int im = 0; im < 4; ++im)
#pragma unroll
        for (int in_ = 0; in_ < 2; ++in_) acc[mq][nq][im][in_] = (f32x4){0.f, 0.f, 0.f, 0.f};

  bf16x8 af[4][2];                  // A frags for current mq
  bf16x8 bf0[2][2], bf1[2][2];      // B frags, both nq halves held

  // stage one 128-row half-tile (2 gload_lds issues per thread)
  auto stA = [&](int buf, int half, int kt) {
    const bf16* g = A + (size_t)(row0 + half * 128 + w * 8 + lrow) * K + kt * 64 + lk * 8;
    bf16* s = &As[buf][(half * 128 + w * 8) * 64 + l * 8];
    gload_lds16(g, s);
    gload_lds16(g + (size_t)64 * K, s + 64 * 64);
  };
  auto stB = [&](int buf, int half, int kt) {
    const bf16* g = Bm + (size_t)(col0 + half * 128 + w * 8 + lrow) * K + kt * 64 + lk * 8;
    bf16* s = &Bs[buf][(half * 128 + w * 8) * 64 + l * 8];
    gload_lds16(g, s);
    gload_lds16(g + (size_t)64 * K, s + 64 * 64);
  };

  auto loadA = [&](const bf16* Ap, int mq) {
#pragma unroll
    for (int im = 0; im < 4; ++im)
#pragma unroll
      for (int kk = 0; kk < 2; ++kk)
        af[im][kk] = *(const bf16x8*)&Ap[(wm + mq * 64 + im * 16 + lane16) * 64 +
                                         (((kk * 4 + quad) ^ sw) * 8)];
  };
  auto loadB = [&](const bf16* Bp, bf16x8 (&dst)[2][2], int nq) {
#pragma unroll
    for (int in_ = 0; in_ < 2; ++in_)
#pragma unroll
      for (int kk = 0; kk < 2; ++kk)
        dst[in_][kk] = *(const bf16x8*)&Bp[(wn + nq * 32 + in_ * 16 + lane16) * 64 +
                                           (((kk * 4 + quad) ^ sw) * 8)];
  };
  auto mma = [&](bf16x8 (&b)[2][2], f32x4 (&ac)[4][2]) {
#pragma unroll
    for (int im = 0; im < 4; ++im)
#pragma unroll
      for (int in_ = 0; in_ < 2; ++in_) {
        ac[im][in_] = __builtin_amdgcn_mfma_f32_16x16x32_bf16(af[im][0], b[in_][0], ac[im][in_], 0, 0, 0);
        ac[im][in_] = __builtin_amdgcn_mfma_f32_16x16x32_bf16(af[im][1], b[in_][1], ac[im][in_], 0, 0, 0);
      }
  };

  const int nt = K >> 6;

  // ---- prologue: tile0 complete + 3 half-tiles of tile1 in flight ----
  stB(0, 0, 0); stB(0, 1, 0); stA(0, 0, 0); stA(0, 1, 0);
  stB(1, 0, 1); stB(1, 1, 1); stA(1, 0, 1);
  asm volatile("s_waitcnt vmcnt(6)" ::: "memory");
  __builtin_amdgcn_s_barrier();

  for (int t = 0; t < nt; ++t) {
    const int p = t & 1;
    const bf16* Ap = As[p];
    const bf16* Bp = Bs[p];

    // ---- phase 1: quadrant (M0,N0); issue (t+1).A1 -> buf p^1 ----
    loadA(Ap, 0);
    loadB(Bp, bf0, 0);
    if (t + 1 < nt) stA(p ^ 1, 1, t + 1);
    __builtin_amdgcn_sched_barrier(0);
    __builtin_amdgcn_s_barrier();
    asm volatile("s_waitcnt lgkmcnt(0)" ::: "memory");
    __builtin_amdgcn_sched_barrier(0);
    __builtin_amdgcn_s_setprio(1);
    mma(bf0, acc[0][0]);
    __builtin_amdgcn_s_setprio(0);
    __builtin_amdgcn_sched_barrier(0);
    __builtin_amdgcn_s_barrier();

    // ---- phase 2: quadrant (M0,N1) ----
    loadB(Bp, bf1, 1);
    __builtin_amdgcn_sched_barrier(0);
    __builtin_amdgcn_s_barrier();
    asm volatile("s_waitcnt lgkmcnt(0)" ::: "memory");
    __builtin_amdgcn_sched_barrier(0);
    __builtin_amdgcn_s_setprio(1);
    mma(bf1, acc[0][1]);
    __builtin_amdgcn_s_setprio(0);
    __builtin_amdgcn_sched_barrier(0);
    __builtin_amdgcn_s_barrier();

    // ---- phase 3: quadrant (M1,N1); issue (t+2).B0,B1 -> buf p (B retired) ----
    loadA(Ap, 1);
    if (t + 2 < nt) { stB(p, 0, t + 2); stB(p, 1, t + 2); }
    __builtin_amdgcn_sched_barrier(0);
    __builtin_amdgcn_s_barrier();
    asm volatile("s_waitcnt lgkmcnt(0)" ::: "memory");
    __builtin_amdgcn_sched_barrier(0);
    __builtin_amdgcn_s_setprio(1);
    mma(bf1, acc[1][1]);
    __builtin_amdgcn_s_setprio(0);
    __builtin_amdgcn_sched_barrier(0);
    __builtin_amdgcn_s_barrier();

    // ---- phase 4: quadrant (M1,N0) from held regs; issue (t+2).A0 -> buf p ----
    if (t + 2 < nt) stA(p, 0, t + 2);
    __builtin_amdgcn_sched_barrier(0);
    __builtin_amdgcn_s_barrier();
    __builtin_amdgcn_s_setprio(1);
    mma(bf0, acc[1][0]);
    __builtin_amdgcn_s_setprio(0);
    __builtin_amdgcn_sched_barrier(0);
    if (t + 2 < nt) asm volatile("s_waitcnt vmcnt(6)" ::: "memory");
    else            asm volatile("s_waitcnt vmcnt(0)" ::: "memory");
    __builtin_amdgcn_s_barrier();
  }

  // ---- epilogue ----
#pragma unroll
  for (int mq = 0; mq < 2; ++mq)
#pragma unroll
    for (int im = 0; im < 4; ++im)
#pragma unroll
      for (int r = 0; r < 4; ++r) {
        int row = row0 + wm + mq * 64 + im * 16 + quad * 4 + r;
        OutT* cp = C + (size_t)row * N + col0 + wn;
#pragma unroll
        for (int nq = 0; nq < 2; ++nq)
#pragma unroll
          for (int in_ = 0; in_ < 2; ++in_)
            cp[nq * 32 + in_ * 16 + lane16] = (OutT)acc[mq][nq][im][in_][r];
      }
}

// ---------------- per-head RMSNorm + RoPE, in-place on qkv (bf16) ----------------
__global__ __launch_bounds__(256) void norm_rope_kernel(
    bf16* __restrict__ qkv, const int* __restrict__ pos,
    const float* __restrict__ qw, const float* __restrict__ kw)
{
  int g = blockIdx.x * 4 + (threadIdx.x >> 6);
  int tok = g / 40;
  int slot = g % 40;
  int d = threadIdx.x & 63;  // pair index
  bf16* base;
  const float* w;
  if (slot < 32) { base = qkv + (size_t)tok * QKV_N + slot * 128; w = qw; }
  else           { base = qkv + (size_t)tok * QKV_N + HID + (slot - 32) * 128; w = kw; }
  float x1 = (float)base[d], x2 = (float)base[d + 64];
  float ss = x1 * x1 + x2 * x2;
#pragma unroll
  for (int m = 1; m < 64; m <<= 1) ss += __shfl_xor(ss, m, 64);
  float rn = rsqrtf(ss * (1.0f / 128.0f) + 1e-6f);
  x1 = x1 * rn * w[d];
  x2 = x2 * rn * w[d + 64];
  int p = pos[tok & 1023];
  float invf = exp2f(-0.20762050593045952f * (float)d);
  float ang = (float)p * invf;
  float sn, c;
  sincosf(ang, &sn, &c);
  base[d]      = (bf16)(x1 * c - x2 * sn);
  base[d + 64] = (bf16)(x2 * c + x1 * sn);
}

// ---------------- flash attention (causal, GQA) ----------------
// grid: (16, 128). qt swizzled so co-resident blocks (ids +256k) pair qt with
// 15-qt -> constant causal work per CU. Q in registers; K/V double-buffered
// with ONE __syncthreads per iter; K prefetched a full iteration ahead via
// global_load_lds; V prefetched to regs at iter top, LDS-written after QK^T.
__global__ __launch_bounds__(256) void flash_kernel(
    const bf16* __restrict__ qkv, bf16* __restrict__ attn)
{
  __shared__ bf16 Ks[2][64 * 128];  // XOR-swizzled rows
  __shared__ bf16 Vt[2][128 * 64];  // [d][t], XOR-swizzled octets
  __shared__ bf16 Ps[4][16 * 72];   // per-wave P (C-layout -> A-layout)

  const int bh = blockIdx.y;        // 0..127
  const int qt = ((bh >> 4) & 1) ? (15 - blockIdx.x) : blockIdx.x;
  const int batch = bh >> 5;
  const int qh = bh & 31;
  const int kvh = qh >> 2;
  const int tid = threadIdx.x;
  const int w = tid >> 6, l = tid & 63;
  const int quad = l >> 4, lane16 = l & 15;
  const int sw = lane16 & 7;
  const size_t tok0 = (size_t)batch * 1024;
  const int q0 = qt * 64;

  // Q fragments from global: A[m=lane16][k=quad*8+j], rows q0 + w*16 + lane16
  bf16x8 qf[4];
  {
    const bf16* qrow = qkv + (tok0 + q0 + w * 16 + lane16) * QKV_N + qh * 128 + quad * 8;
#pragma unroll
    for (int kk = 0; kk < 4; ++kk) qf[kk] = *(const bf16x8*)(qrow + kk * 32);
  }

  f32x4 O[8];
#pragma unroll
  for (int id = 0; id < 8; ++id) O[id] = (f32x4){0.f, 0.f, 0.f, 0.f};
  float m_run[4], l_run[4];
#pragma unroll
  for (int r = 0; r < 4; ++r) { m_run[r] = -1e30f; l_run[r] = 0.f; }

  const float scale = 0.08838834764831845f;  // 1/sqrt(128)
  bf16x8 vreg[4];

  // ---- staging helpers ----
  auto stage_K = [&](int j, int buf) {
#pragma unroll
    for (int r = 0; r < 4; ++r) {
      int i = r * 4 + w;
      int rloc = i * 4 + (l >> 4);
      int o = (l & 15) ^ (rloc & 7);
      const bf16* g = qkv + (tok0 + j * 64 + rloc) * QKV_N + HID + kvh * 128 + o * 8;
      gload_lds16(g, &Ks[buf][i * 512 + l * 8]);
    }
  };
  auto load_V = [&](int j) {
#pragma unroll
    for (int c = 0; c < 4; ++c) {
      int d0 = (c * 4 + w) * 8;
      vreg[c] = *(const bf16x8*)(qkv + (tok0 + j * 64 + l) * QKV_N + HID + 1024 + kvh * 128 + d0);
    }
  };
  auto write_V = [&](int buf) {
#pragma unroll
    for (int c = 0; c < 4; ++c) {
      int d0 = (c * 4 + w) * 8;
#pragma unroll
      for (int e = 0; e < 8; ++e) {
        int d = d0 + e;
        Vt[buf][d * 64 + (((l >> 3) ^ (d & 7)) * 8) + (l & 7)] = vreg[c][e];
      }
    }
  };

  // prologue: stage j=0 into buf 0
  stage_K(0, 0);
  load_V(0);
  write_V(0);
  __syncthreads();

  for (int j = 0; j <= qt; ++j) {
    const int p = j & 1;
    // prefetch next tile (K direct to LDS, V to regs)
    if (j < qt) { stage_K(j + 1, p ^ 1); load_V(j + 1); }

    // S = Q K^T
    f32x4 s[4];
#pragma unroll
    for (int in_ = 0; in_ < 4; ++in_) s[in_] = (f32x4){0.f, 0.f, 0.f, 0.f};
#pragma unroll
    for (int kk = 0; kk < 4; ++kk) {
#pragma unroll
      for (int in_ = 0; in_ < 4; ++in_) {
        bf16x8 b = *(const bf16x8*)&Ks[p][(in_ * 16 + lane16) * 128 + (((kk * 4 + quad) ^ sw) * 8)];
        s[in_] = __builtin_amdgcn_mfma_f32_16x16x32_bf16(qf[kk], b, s[in_], 0, 0, 0);
      }
    }

    // V(j+1) regs -> LDS (overlaps with the vm latency already mostly hidden by QK)
    if (j < qt) write_V(p ^ 1);

    // softmax (mask only on diagonal tile)
    const bool edge = (j == qt);
#pragma unroll
    for (int r = 0; r < 4; ++r) {
      float rm = -1e30f;
#pragma unroll
      for (int in_ = 0; in_ < 4; ++in_) {
        float v = s[in_][r] * scale;
        if (edge) {
          int t_abs = j * 64 + in_ * 16 + lane16;
          int q_abs = q0 + w * 16 + quad * 4 + r;
          v = (t_abs <= q_abs) ? v : -1e30f;
        }
        s[in_][r] = v;
        rm = fmaxf(rm, v);
      }
#pragma unroll
      for (int m = 1; m < 16; m <<= 1) rm = fmaxf(rm, __shfl_xor(rm, m, 64));
      float mn = fmaxf(m_run[r], rm);
      float alpha = __expf(m_run[r] - mn);
      m_run[r] = mn;
      float rs = 0.f;
#pragma unroll
      for (int in_ = 0; in_ < 4; ++in_) {
        float pv = __expf(s[in_][r] - mn);
        s[in_][r] = pv;
        rs += pv;
      }
#pragma unroll
      for (int m = 1; m < 16; m <<= 1) rs += __shfl_xor(rs, m, 64);
      l_run[r] = l_run[r] * alpha + rs;
#pragma unroll
      for (int id = 0; id < 8; ++id) O[id][r] *= alpha;
#pragma unroll
      for (int in_ = 0; in_ < 4; ++in_)
        Ps[w][(quad * 4 + r) * 72 + in_ * 16 + lane16] = (bf16)s[in_][r];
    }

    // O += P @ V  (Ps is per-wave: no barrier needed, lgkmcnt dependency only)
#pragma unroll
    for (int kt = 0; kt < 2; ++kt) {
      bf16x8 a = *(const bf16x8*)&Ps[w][lane16 * 72 + kt * 32 + quad * 8];
#pragma unroll
      for (int id = 0; id < 8; ++id) {
        bf16x8 b = *(const bf16x8*)&Vt[p][(id * 16 + lane16) * 64 + (((kt * 4 + quad) ^ sw) * 8)];
        O[id] = __builtin_amdgcn_mfma_f32_16x16x32_bf16(a, b, O[id], 0, 0, 0);
      }
    }
    __syncthreads();  // buf p free for overwrite; prefetched vmcnt drained
  }

  // epilogue
#pragma unroll
  for (int r = 0; r < 4; ++r) {
    float inv = 1.0f / l_run[r];
    int row = q0 + w * 16 + quad * 4 + r;
    bf16* orow = attn + (tok0 + row) * (size_t)HID + qh * 128;
#pragma unroll
    for (int id = 0; id < 8; ++id) orow[id * 16 + lane16] = (bf16)(O[id][r] * inv);
  }
}

// ---------------- launch ----------------
extern "C" void kernel_launch(void* const* d_in, const int* in_sizes, int n_in,
                              void* d_out, int out_size, void* d_ws, size_t ws_size,
                              hipStream_t stream) {
  const float* h    = (const float*)d_in[0];
  const int*   pos  = (const int*)d_in[1];
  const float* wqkv = (const float*)d_in[2];
  const float* wo   = (const float*)d_in[3];
  const float* qw   = (const float*)d_in[4];
  const float* kw   = (const float*)d_in[5];
  float* out = (float*)d_out;

  bf16* hb    = (bf16*)d_ws;
  bf16* wqkvb = hb + 16777216;
  bf16* wob   = wqkvb + 25165824;
  bf16* qkvb  = wob + 16777216;
  bf16* attnb = qkvb + 25165824;

  cvt_kernel<<<16384, 256, 0, stream>>>((const float4*)h, (bf16x4*)hb);
  cvt_kernel<<<24576, 256, 0, stream>>>((const float4*)wqkv, (bf16x4*)wqkvb);
  cvt_kernel<<<16384, 256, 0, stream>>>((const float4*)wo, (bf16x4*)wob);

  // QKV projection: M=4096, N=6144, K=4096 -> grid 24x16 = 384 wgs (%8==0)
  gemm_bt256<bf16><<<dim3(24, 16), 512, 0, stream>>>(hb, wqkvb, qkvb, NTOK, QKV_N, HID);

  norm_rope_kernel<<<NTOK * 40 / 4, 256, 0, stream>>>(qkvb, pos, qw, kw);

  flash_kernel<<<dim3(16, 128), 256, 0, stream>>>(qkvb, attnb);

  // Output projection: M=4096, N=4096, K=4096 -> grid 16x16 = 256 wgs (1 full round)
  gemm_bt256<float><<<dim3(16, 16), 512, 0, stream>>>(attnb, wob, out, NTOK, HID, HID);
}